// Round 21
// baseline (117.197 us; speedup 1.0000x reference)
//
#include <hip/hip_runtime.h>
#include <hip/hip_bf16.h>
#include <math.h>

namespace {

constexpr int kB = 32;
constexpr int kS = 2048;
constexpr int kI = 32;
constexpr int kW = 20;
constexpr int kH = 128;
constexpr int kNwin = kS - kW + 1;   // 2029
constexpr int kT = kS - 2 * kW;      // 2008
constexpr float kEps = 1e-5f;
constexpr int FCAP = 16384;
constexpr float kMargin = 3e-3f;     // fp16 1-pass p-error bound ~5e-4 << 3e-3

typedef __attribute__((ext_vector_type(8))) _Float16 half8;       // 8 f16 (4 VGPR)
typedef __attribute__((ext_vector_type(8))) unsigned short ush8;  // 16B unit
typedef __attribute__((ext_vector_type(4))) float f32x4;

// async global->LDS DMA, 16B per lane; dest = uniform base + lane*16 (linear)
#define GLD16(SRC, DST)                                                          \
    __builtin_amdgcn_global_load_lds(                                            \
        (const __attribute__((address_space(1))) unsigned*)(const void*)(SRC),   \
        (__attribute__((address_space(3))) unsigned*)(void*)(DST), 16, 0, 0)

__device__ __forceinline__ unsigned short f2h(float f) {          // RNE f32->f16
    _Float16 h = (_Float16)f;
    return __builtin_bit_cast(unsigned short, h);
}
__device__ __forceinline__ float gelu_exact(float v) {
    return 0.5f * v * (1.0f + erff(v * 0.70710678118654752440f));
}

// ---- workspace layout (bytes) ----
constexpr size_t ENCB_OFF = 0;                        // enc f16: 32*2048*128*2 = 16 MB
constexpr size_t WEF_OFF  = 16777216;                 // WencF frag-major [20][4][128][8]
constexpr size_t W1F_OFF  = WEF_OFF + 163840;         // W1F [4][2][4][128][8]
constexpr size_t W2F_OFF  = W1F_OFF + 65536;          // W2F [2][2][4][64][8]
constexpr size_t FC_OFF   = W2F_OFF + 16384;
constexpr size_t FL_OFF   = FC_OFF + 64;              // flist FCAP u32 (64 KB)

// ================= prep: frag-major f16 W layouts =================
__global__ void prep_kernel(const float* __restrict__ Wenc, const float* __restrict__ W1,
                            const float* __restrict__ W2,
                            unsigned short* __restrict__ WeF, unsigned short* __restrict__ W1F,
                            unsigned short* __restrict__ W2F)
{
    const int tid = blockIdx.x * blockDim.x + threadIdx.x;
    const int nth = gridDim.x * blockDim.x;
    for (int i = tid; i < 20 * 4 * 128 * 8; i += nth) {
        int j = i & 7, n = (i >> 3) & 127, rg = (i >> 10) & 3, kc = i >> 12;
        int k = kc * 32 + rg * 8 + j;
        WeF[i] = f2h(Wenc[(size_t)k * kH + n]);
    }
    for (int i = tid; i < 4 * 2 * 4 * 128 * 8; i += nth) {
        int j = i & 7, n = (i >> 3) & 127, rg = (i >> 10) & 3, ks = (i >> 12) & 1, kc = i >> 13;
        int k = kc * 64 + ks * 32 + rg * 8 + j;
        W1F[i] = f2h(W1[(size_t)k * kH + n]);
    }
    for (int i = tid; i < 2 * 2 * 4 * 64 * 8; i += nth) {
        int j = i & 7, n = (i >> 3) & 63, rg = (i >> 9) & 3, ks = (i >> 11) & 1, kc2 = i >> 12;
        int k = kc2 * 64 + ks * 32 + rg * 8 + j;
        W2F[i] = f2h(W2[(size_t)k * 64 + n]);
    }
}

// ================= encoder: f16 MFMA + LN + GELU (512 thr, 2D wave tile) =================
constexpr int AP = 40;    // x LDS pitch in ushorts (80B)

__global__ __launch_bounds__(512, 4)
void enc_kernel(const float* __restrict__ x, const unsigned short* __restrict__ WeF,
                const float* __restrict__ benc, const float* __restrict__ gma,
                const float* __restrict__ bta, unsigned short* __restrict__ encb)
{
    __shared__ unsigned short xsh[147 * AP];
    __shared__ unsigned short wth[4096];
    __shared__ float red[2][128][2];

    const int tid = threadIdx.x, b = blockIdx.y, t0 = blockIdx.x * 128;
    const int l = tid & 63, w = tid >> 6;
    const int wr = w >> 1, wc = w & 1;
    const int cb = l & 15, rg = l >> 4;

    const float4* x4 = reinterpret_cast<const float4*>(x + (size_t)b * kS * kI);
    for (int i = tid; i < 147 * 8; i += 512) {
        int r = i >> 3, q = i & 7;
        int gr = t0 + r; if (gr > kS - 1) gr = kS - 1;
        float4 v = x4[gr * 8 + q];
        unsigned short h0 = f2h(v.x), h1 = f2h(v.y), h2 = f2h(v.z), h3 = f2h(v.w);
        *reinterpret_cast<uint2*>(&xsh[r * AP + q * 4]) =
            make_uint2((unsigned)h0 | ((unsigned)h1 << 16), (unsigned)h2 | ((unsigned)h3 << 16));
    }

    f32x4 acc[2][4];
    #pragma unroll
    for (int mi = 0; mi < 2; ++mi)
        #pragma unroll
        for (int nf = 0; nf < 4; ++nf) acc[mi][nf] = f32x4{0.f, 0.f, 0.f, 0.f};

    for (int kc = 0; kc < 20; ++kc) {
        __syncthreads();
        GLD16(WeF + (size_t)kc * 4096 + w * 512 + l * 8, &wth[w * 512]);
        __syncthreads();
        const int a0o = (wr * 32 + cb + kc) * AP + rg * 8;
        half8 a0 = *reinterpret_cast<const half8*>(&xsh[a0o]);
        half8 a1 = *reinterpret_cast<const half8*>(&xsh[a0o + 16 * AP]);
        #pragma unroll
        for (int nf = 0; nf < 4; ++nf) {
            const int bo = rg * 1024 + (wc * 64 + nf * 16 + cb) * 8;
            half8 bh = *reinterpret_cast<const half8*>(&wth[bo]);
            acc[0][nf] = __builtin_amdgcn_mfma_f32_16x16x32_f16(a0, bh, acc[0][nf], 0, 0, 0);
            acc[1][nf] = __builtin_amdgcn_mfma_f32_16x16x32_f16(a1, bh, acc[1][nf], 0, 0, 0);
        }
    }

    float bv[4], gv[4], btv[4];
    #pragma unroll
    for (int nf = 0; nf < 4; ++nf) {
        const int col = wc * 64 + nf * 16 + cb;
        bv[nf] = benc[col]; gv[nf] = gma[col]; btv[nf] = bta[col];
    }
    float h[2][4][4];
    #pragma unroll
    for (int mi = 0; mi < 2; ++mi)
        #pragma unroll
        for (int r = 0; r < 4; ++r) {
            float s = 0.f;
            #pragma unroll
            for (int nf = 0; nf < 4; ++nf) {
                h[mi][r][nf] = acc[mi][nf][r] + bv[nf];
                s += h[mi][r][nf];
            }
            s += __shfl_xor(s, 1); s += __shfl_xor(s, 2);
            s += __shfl_xor(s, 4); s += __shfl_xor(s, 8);
            if (cb == 0) red[0][wr * 32 + mi * 16 + rg * 4 + r][wc] = s;
        }
    __syncthreads();
    #pragma unroll
    for (int mi = 0; mi < 2; ++mi)
        #pragma unroll
        for (int r = 0; r < 4; ++r) {
            const int rl = wr * 32 + mi * 16 + rg * 4 + r;
            const float mu = (red[0][rl][0] + red[0][rl][1]) * (1.f / 128.f);
            float s2 = 0.f;
            #pragma unroll
            for (int nf = 0; nf < 4; ++nf) {
                h[mi][r][nf] -= mu;
                s2 += h[mi][r][nf] * h[mi][r][nf];
            }
            s2 += __shfl_xor(s2, 1); s2 += __shfl_xor(s2, 2);
            s2 += __shfl_xor(s2, 4); s2 += __shfl_xor(s2, 8);
            if (cb == 0) red[1][rl][wc] = s2;
        }
    __syncthreads();
    #pragma unroll
    for (int mi = 0; mi < 2; ++mi)
        #pragma unroll
        for (int r = 0; r < 4; ++r) {
            const int rl = wr * 32 + mi * 16 + rg * 4 + r;
            const int t = t0 + rl;
            const float var = (red[1][rl][0] + red[1][rl][1]) * (1.f / 128.f);
            const float rstd = 1.f / sqrtf(var + kEps);
            if (t < kNwin) {
                unsigned short* dst = encb + ((size_t)(b * kS + t)) * kH;
                #pragma unroll
                for (int nf = 0; nf < 4; ++nf) {
                    float v = gelu_exact(h[mi][r][nf] * rstd * gv[nf] + btv[nf]);
                    dst[wc * 64 + nf * 16 + cb] = f2h(v);
                }
            }
        }
}

// ================= comparator (512 thr): L1 16r x 64c, L2 16r x 32c =================
constexpr int EPP = 72;

__global__ __launch_bounds__(512, 4)
void cmp_kernel(const unsigned short* __restrict__ encb,
                const unsigned short* __restrict__ W1F, const float* __restrict__ b1,
                const unsigned short* __restrict__ W2F, const float* __restrict__ b2,
                const float* __restrict__ W3, const float* __restrict__ b3,
                float* __restrict__ out, int* __restrict__ fcnt, unsigned* __restrict__ flist)
{
    __shared__ __align__(16) unsigned short pool[12800];
    __shared__ float prm[192];

    unsigned short* esh  = pool;
    unsigned short* wt1h = pool + 4608;

    const int tid = threadIdx.x, b = blockIdx.y, t0 = blockIdx.x * 64;
    const int l = tid & 63, w = tid >> 6;
    const int wr = w >> 1, wc = w & 1;
    const int cb = l & 15, rg = l >> 4;

    if (tid < 128) prm[tid] = b1[tid];
    else if (tid < 192) prm[tid] = b2[tid - 128];

    f32x4 acc1[4];
    #pragma unroll
    for (int nf = 0; nf < 4; ++nf) acc1[nf] = f32x4{0.f, 0.f, 0.f, 0.f};

    for (int kc = 0; kc < 4; ++kc) {
        const int ro = (kc < 2) ? 0 : kW, co = (kc & 1) * 64;
        __syncthreads();
        GLD16(W1F + (size_t)kc * 8192 + w * 512 + l * 8, &wt1h[w * 512]);
        GLD16(W1F + (size_t)kc * 8192 + 4096 + w * 512 + l * 8, &wt1h[4096 + w * 512]);
        {
            const int r = tid >> 3, qq = tid & 7;
            int gr = t0 + ro + r; if (gr > kNwin - 1) gr = kNwin - 1;
            *reinterpret_cast<ush8*>(&esh[r * EPP + qq * 8]) =
                *reinterpret_cast<const ush8*>(encb + ((size_t)(b * kS + gr)) * kH + co + qq * 8);
        }
        __syncthreads();
        #pragma unroll
        for (int ks = 0; ks < 2; ++ks) {
            const int ao = (wr * 16 + cb) * EPP + ks * 32 + rg * 8;
            half8 ah = *reinterpret_cast<const half8*>(&esh[ao]);
            #pragma unroll
            for (int nf = 0; nf < 4; ++nf) {
                const int bo = (ks * 4 + rg) * 1024 + (wc * 64 + nf * 16 + cb) * 8;
                half8 bh = *reinterpret_cast<const half8*>(&wt1h[bo]);
                acc1[nf] = __builtin_amdgcn_mfma_f32_16x16x32_f16(ah, bh, acc1[nf], 0, 0, 0);
            }
        }
    }
    __syncthreads();
    unsigned short* z1h = pool;
    unsigned short* w2h = pool + 8704;
    #pragma unroll
    for (int r = 0; r < 4; ++r) {
        const int row = wr * 16 + rg * 4 + r;
        #pragma unroll
        for (int nf = 0; nf < 4; ++nf) {
            const int col = wc * 64 + nf * 16 + cb;
            z1h[row * 136 + col] = f2h(gelu_exact(acc1[nf][r] + prm[col]));
        }
    }

    f32x4 acc2[2];
    #pragma unroll
    for (int nf = 0; nf < 2; ++nf) acc2[nf] = f32x4{0.f, 0.f, 0.f, 0.f};

    for (int kc2 = 0; kc2 < 2; ++kc2) {
        __syncthreads();
        GLD16(W2F + (size_t)kc2 * 4096 + w * 512 + l * 8, &w2h[w * 512]);
        __syncthreads();
        #pragma unroll
        for (int ks = 0; ks < 2; ++ks) {
            const int ao = (wr * 16 + cb) * 136 + kc2 * 64 + ks * 32 + rg * 8;
            half8 ah = *reinterpret_cast<const half8*>(&z1h[ao]);
            #pragma unroll
            for (int nf = 0; nf < 2; ++nf) {
                const int bo = (ks * 4 + rg) * 512 + (wc * 32 + nf * 16 + cb) * 8;
                half8 bh = *reinterpret_cast<const half8*>(&w2h[bo]);
                acc2[nf] = __builtin_amdgcn_mfma_f32_16x16x32_f16(ah, bh, acc2[nf], 0, 0, 0);
            }
        }
    }
    __syncthreads();
    float* z2f = reinterpret_cast<float*>(pool);
    #pragma unroll
    for (int r = 0; r < 4; ++r) {
        const int row = wr * 16 + rg * 4 + r;
        #pragma unroll
        for (int nf = 0; nf < 2; ++nf) {
            const int col = wc * 32 + nf * 16 + cb;
            z2f[row * 68 + col] = gelu_exact(acc2[nf][r] + prm[128 + col]);
        }
    }
    __syncthreads();

    if (tid < 64) {
        const int t = t0 + tid;
        if (t < kT) {
            float s = 0.f;
            #pragma unroll 8
            for (int k = 0; k < 64; ++k) s = fmaf(z2f[tid * 68 + k], W3[k], s);
            const float p = 1.f / (1.f + expf(-(s + b3[0])));
            out[(size_t)b * kS + t + kW] = p;
            out[(size_t)kB * kS + (size_t)b * kS + t + kW] = (p > 0.5f) ? 1.f : 0.f;
            if (fabsf(p - 0.5f) < kMargin) {
                int idx = atomicAdd(fcnt, 1);
                if (idx < FCAP) flist[idx] = ((unsigned)b << 16) | (unsigned)t;
            }
        }
    }
}

// ================= fix5: fp32 recompute, 8 pos/block, PING-PONG W DMA =================
// threads: p = tid>>5 (position), cq = tid&31 (4 cols each). Chunks of 32 k-rows (16 KB).
__global__ __launch_bounds__(256, 2)
void fix5_kernel(const float* __restrict__ x, const float* __restrict__ Wenc,
                 const float* __restrict__ benc, const float* __restrict__ gma,
                 const float* __restrict__ bta, const float* __restrict__ W1,
                 const float* __restrict__ b1, const float* __restrict__ W2,
                 const float* __restrict__ b2, const float* __restrict__ W3,
                 const float* __restrict__ b3, const int* __restrict__ fcnt,
                 const unsigned* __restrict__ flist, float* __restrict__ out)
{
    __shared__ float Wc[2][4096];     // 2 x 16 KB ping-pong W chunk [kk<32][cols]
    __shared__ float xwc[2][16][32];  // 2 x 2 KB: [buf][r*8+p][kk]
    __shared__ float es[8][256];      // 8 KB
    __shared__ float z1s[8][128];     // 4 KB
    __shared__ float z2s[8][64];      // 2 KB
    __shared__ unsigned pbt[8];

    const int tid = threadIdx.x;
    const int wv = tid >> 6, l = tid & 63;
    const int p = tid >> 5, cq = tid & 31;
    const int rp = tid >> 3, xq = tid & 7;   // x stager: rp<16 rows, 8 float4 each (tid<128)
    int n = *fcnt; if (n > FCAP) n = FCAP;
    if (n <= 0) return;
    const int nb = (n + 7) >> 3;

#define DMA_W32(SRC, BUF)                                                        \
    {   const float* _s = (SRC);                                                 \
        _Pragma("unroll")                                                        \
        for (int q = 0; q < 4; ++q)                                              \
            GLD16(_s + (wv * 4 + q) * 256 + l * 4, &Wc[BUF][(wv * 4 + q) * 256]); }

    for (int ib = blockIdx.x; ib < nb; ib += gridDim.x) {
        __syncthreads();
        if (tid < 8) {
            int idx = ib * 8 + tid; if (idx > n - 1) idx = n - 1;
            pbt[tid] = flist[idx];
        }
        __syncthreads();

        // per-thread x-stager source base (row r, position pp)
        int xbase = 0;
        if (tid < 128) {
            const int r = rp >> 3, pp = rp & 7;
            const unsigned e = pbt[pp];
            xbase = (((int)(e >> 16)) * kS + (int)(e & 0xFFFF) + r * kW) * kI;
        }

        // ================= encoder GEMM: K=640 in 20 chunks of 32, ping-pong =================
        float acc[2][4];
        #pragma unroll
        for (int r = 0; r < 2; ++r)
            #pragma unroll
            for (int j = 0; j < 4; ++j) acc[r][j] = 0.f;

        // prologue: chunk 0 -> buf 0
        float4 xreg;
        if (tid < 128) xreg = *reinterpret_cast<const float4*>(x + xbase + xq * 4);
        DMA_W32(Wenc + 0, 0);
        if (tid < 128) *reinterpret_cast<float4*>(&xwc[0][rp][xq * 4]) = xreg;
        __syncthreads();

        for (int kc = 0; kc < 20; ++kc) {
            const int cur = kc & 1;
            if (kc < 19) {   // issue next-chunk loads EARLY (overlap with compute)
                if (tid < 128)
                    xreg = *reinterpret_cast<const float4*>(x + xbase + (kc + 1) * 32 + xq * 4);
                DMA_W32(Wenc + (size_t)(kc + 1) * 4096, cur ^ 1);
            }
            #pragma unroll 4
            for (int kk = 0; kk < 32; ++kk) {
                const float a0 = xwc[cur][p][kk];
                const float a1 = xwc[cur][8 + p][kk];
                const float4 wv4 = *reinterpret_cast<const float4*>(&Wc[cur][kk * 128 + cq * 4]);
                acc[0][0] = fmaf(a0, wv4.x, acc[0][0]);
                acc[0][1] = fmaf(a0, wv4.y, acc[0][1]);
                acc[0][2] = fmaf(a0, wv4.z, acc[0][2]);
                acc[0][3] = fmaf(a0, wv4.w, acc[0][3]);
                acc[1][0] = fmaf(a1, wv4.x, acc[1][0]);
                acc[1][1] = fmaf(a1, wv4.y, acc[1][1]);
                acc[1][2] = fmaf(a1, wv4.z, acc[1][2]);
                acc[1][3] = fmaf(a1, wv4.w, acc[1][3]);
            }
            if (kc < 19 && tid < 128)
                *reinterpret_cast<float4*>(&xwc[cur ^ 1][rp][xq * 4]) = xreg;   // write-late
            __syncthreads();   // drains DMA (vmcnt0) + ds_writes; next buf ready
        }

        // ---- LN + GELU (per (p,r) row; row lives in one 32-lane group)
        const float4 bv = *reinterpret_cast<const float4*>(benc + cq * 4);
        const float4 gv = *reinterpret_cast<const float4*>(gma + cq * 4);
        const float4 bt = *reinterpret_cast<const float4*>(bta + cq * 4);
        #pragma unroll
        for (int r = 0; r < 2; ++r) {
            float hv[4];
            hv[0] = acc[r][0] + bv.x; hv[1] = acc[r][1] + bv.y;
            hv[2] = acc[r][2] + bv.z; hv[3] = acc[r][3] + bv.w;
            float s = hv[0] + hv[1] + hv[2] + hv[3];
            s += __shfl_xor(s, 1); s += __shfl_xor(s, 2); s += __shfl_xor(s, 4);
            s += __shfl_xor(s, 8); s += __shfl_xor(s, 16);
            const float mu = s * (1.f / 128.f);
            float s2 = 0.f;
            #pragma unroll
            for (int j = 0; j < 4; ++j) { hv[j] -= mu; s2 += hv[j] * hv[j]; }
            s2 += __shfl_xor(s2, 1); s2 += __shfl_xor(s2, 2); s2 += __shfl_xor(s2, 4);
            s2 += __shfl_xor(s2, 8); s2 += __shfl_xor(s2, 16);
            const float rstd = 1.f / sqrtf(s2 * (1.f / 128.f) + kEps);
            *reinterpret_cast<float4*>(&es[p][r * 128 + cq * 4]) = make_float4(
                gelu_exact(hv[0] * rstd * gv.x + bt.x),
                gelu_exact(hv[1] * rstd * gv.y + bt.y),
                gelu_exact(hv[2] * rstd * gv.z + bt.z),
                gelu_exact(hv[3] * rstd * gv.w + bt.w));
        }

        // ================= layer 1: K=256 in 8 chunks of 32, ping-pong =================
        {
            float z[4] = {0.f, 0.f, 0.f, 0.f};
            __syncthreads();              // enc Wc reads done (last chunk)
            DMA_W32(W1 + 0, 0);
            __syncthreads();
            for (int kc1 = 0; kc1 < 8; ++kc1) {
                const int cur = kc1 & 1;
                if (kc1 < 7) DMA_W32(W1 + (size_t)(kc1 + 1) * 4096, cur ^ 1);
                #pragma unroll 4
                for (int kk = 0; kk < 32; ++kk) {
                    const float a = es[p][kc1 * 32 + kk];
                    const float4 wv4 = *reinterpret_cast<const float4*>(&Wc[cur][kk * 128 + cq * 4]);
                    z[0] = fmaf(a, wv4.x, z[0]);
                    z[1] = fmaf(a, wv4.y, z[1]);
                    z[2] = fmaf(a, wv4.z, z[2]);
                    z[3] = fmaf(a, wv4.w, z[3]);
                }
                __syncthreads();
            }
            const float4 b1v = *reinterpret_cast<const float4*>(b1 + cq * 4);
            *reinterpret_cast<float4*>(&z1s[p][cq * 4]) = make_float4(
                gelu_exact(z[0] + b1v.x), gelu_exact(z[1] + b1v.y),
                gelu_exact(z[2] + b1v.z), gelu_exact(z[3] + b1v.w));
        }

        // ================= layer 2: K=128, N=64 (32 KB -> both Wc halves) =================
        __syncthreads();
        {   // stage whole W2: 32 segments of 1 KB
            #pragma unroll
            for (int q = 0; q < 4; ++q) {
                GLD16(W2 + (wv * 4 + q) * 256 + l * 4, &Wc[0][(wv * 4 + q) * 256]);
                GLD16(W2 + 4096 + (wv * 4 + q) * 256 + l * 4, &Wc[1][(wv * 4 + q) * 256]);
            }
        }
        __syncthreads();
        if (cq < 16) {
            float z[4] = {0.f, 0.f, 0.f, 0.f};
            #pragma unroll 4
            for (int kk = 0; kk < 64; ++kk) {
                const float a = z1s[p][kk];
                const float4 wv4 = *reinterpret_cast<const float4*>(&Wc[0][kk * 64 + cq * 4]);
                z[0] = fmaf(a, wv4.x, z[0]);
                z[1] = fmaf(a, wv4.y, z[1]);
                z[2] = fmaf(a, wv4.z, z[2]);
                z[3] = fmaf(a, wv4.w, z[3]);
            }
            #pragma unroll 4
            for (int kk = 0; kk < 64; ++kk) {
                const float a = z1s[p][64 + kk];
                const float4 wv4 = *reinterpret_cast<const float4*>(&Wc[1][kk * 64 + cq * 4]);
                z[0] = fmaf(a, wv4.x, z[0]);
                z[1] = fmaf(a, wv4.y, z[1]);
                z[2] = fmaf(a, wv4.z, z[2]);
                z[3] = fmaf(a, wv4.w, z[3]);
            }
            const float4 b2v = *reinterpret_cast<const float4*>(b2 + cq * 4);
            *reinterpret_cast<float4*>(&z2s[p][cq * 4]) = make_float4(
                gelu_exact(z[0] + b2v.x), gelu_exact(z[1] + b2v.y),
                gelu_exact(z[2] + b2v.z), gelu_exact(z[3] + b2v.w));
        }
        __syncthreads();

        // ---- layer 3: dot(z2, W3) + sigmoid
        {
            float s = z2s[p][cq] * W3[cq] + z2s[p][cq + 32] * W3[cq + 32];
            s += __shfl_xor(s, 1); s += __shfl_xor(s, 2); s += __shfl_xor(s, 4);
            s += __shfl_xor(s, 8); s += __shfl_xor(s, 16);
            if (cq == 0) {
                const unsigned e = pbt[p];
                const int bb = (int)(e >> 16), tt = (int)(e & 0xFFFF);
                const float pr = 1.f / (1.f + expf(-(s + b3[0])));
                out[(size_t)bb * kS + tt + kW] = pr;
                out[(size_t)kB * kS + (size_t)bb * kS + tt + kW] = (pr > 0.5f) ? 1.f : 0.f;
            }
        }
    }
#undef DMA_W32
}

}  // namespace

extern "C" void kernel_launch(void* const* d_in, const int* in_sizes, int n_in,
                              void* d_out, int out_size, void* d_ws, size_t ws_size,
                              hipStream_t stream)
{
    const float* x    = (const float*)d_in[0];
    const float* Wenc = (const float*)d_in[1];
    const float* benc = (const float*)d_in[2];
    const float* gma  = (const float*)d_in[3];
    const float* bta  = (const float*)d_in[4];
    const float* W1   = (const float*)d_in[5];
    const float* b1   = (const float*)d_in[6];
    const float* W2   = (const float*)d_in[7];
    const float* b2   = (const float*)d_in[8];
    const float* W3   = (const float*)d_in[9];
    const float* b3   = (const float*)d_in[10];
    float* out = (float*)d_out;

    char* ws = (char*)d_ws;
    unsigned short* encb  = (unsigned short*)(ws + ENCB_OFF);
    unsigned short* WeF   = (unsigned short*)(ws + WEF_OFF);
    unsigned short* W1F   = (unsigned short*)(ws + W1F_OFF);
    unsigned short* W2F   = (unsigned short*)(ws + W2F_OFF);
    int* fcnt             = (int*)(ws + FC_OFF);
    unsigned* flist       = (unsigned*)(ws + FL_OFF);

    hipMemsetAsync(d_out, 0, (size_t)out_size * sizeof(float), stream);
    hipMemsetAsync(fcnt, 0, 64, stream);

    prep_kernel<<<256, 256, 0, stream>>>(Wenc, W1, W2, WeF, W1F, W2F);
    enc_kernel<<<dim3(16, kB), 512, 0, stream>>>(x, WeF, benc, gma, bta, encb);
    cmp_kernel<<<dim3(32, kB), 512, 0, stream>>>(encb, W1F, b1, W2F, b2, W3, b3,
                                                 out, fcnt, flist);
    fix5_kernel<<<512, 256, 0, stream>>>(x, Wenc, benc, gma, bta, W1, b1, W2, b2, W3, b3,
                                         fcnt, flist, out);
}